// Round 2
// baseline (989.201 us; speedup 1.0000x reference)
//
#include <hip/hip_runtime.h>
#include <hip/hip_bf16.h>

// ---------------- problem constants ----------------
#define B_    4
#define S_    1024
#define HID   4096
#define H_    32
#define KVH_  8
#define D_    128
#define T_    (B_ * S_)        // 4096
#define QKVD  (H_ * D_ + 2 * KVH_ * D_)  // 6144
#define NSLOT 8192

typedef __attribute__((ext_vector_type(8))) short short8;   // 8 bf16 = 4 VGPRs
typedef __attribute__((ext_vector_type(4))) float f32x4;

#define MFMA_B16(d, x, y) \
  d = __builtin_amdgcn_mfma_f32_16x16x32_bf16(x, y, d, 0, 0, 0)

__device__ __forceinline__ unsigned short f2b(float f) {
  union { __hip_bfloat16 h; unsigned short u; } c;
  c.h = __float2bfloat16(f);
  return c.u;
}
__device__ __forceinline__ float b2f(unsigned short u) {
  union { unsigned int i; float f; } c;
  c.i = ((unsigned int)u) << 16;
  return c.f;
}

// async global->LDS 16B. LDS dest must be wave-uniform base + lane*16.
__device__ __forceinline__ void async16(const void* g, void* l) {
  __builtin_amdgcn_global_load_lds(
      (const __attribute__((address_space(1))) unsigned int*)g,
      (__attribute__((address_space(3))) unsigned int*)l,
      16, 0, 0);
}

// ---------------- fp32 -> bf16 convert ----------------
__global__ void conv_bf16(const float* __restrict__ src,
                          unsigned short* __restrict__ dst, int n4) {
  int i = blockIdx.x * 256 + threadIdx.x;
  if (i >= n4) return;
  float4 v = reinterpret_cast<const float4*>(src)[i];
  ushort4 o;
  o.x = f2b(v.x); o.y = f2b(v.y); o.z = f2b(v.z); o.w = f2b(v.w);
  reinterpret_cast<ushort4*>(dst)[i] = o;
}

// ---------------- GEMM: C(M,N) = A(M,K)bf16 * B(N,K)bf16 ^T ------------------
// m201-faithful 8-phase port: 256x256 tile, BK=64, 8 waves (2M x 4N), 512 thr.
// Per K-tile: 4 phases, each = {ds-read frags, stage 1 half-tile, sched_bar,
// s_barrier, setprio(1), 16 MFMA, setprio(0), s_barrier}. ds_reads issue
// BEFORE the pre-MFMA barrier so LDS latency overlaps the barrier wait
// (round-1 regression: reads after barrier exposed full latency at 2 wv/SIMD).
// ONE vmcnt(2) per K-tile (tail phase), never a drain in the loop.
//
// LDS: As/Bs = [buf2][half2][128 rows][64 k] bf16, 64KB each, 128KB total.
// Stage slots (tile t in buf b, proof in session journal):
//   ph0: A-h1(t+1)->b^1   (b^1 fully consumed in tile t-1, barrier-separated)
//   ph1: B-h0(t+1)->b^1
//   ph2: B-h1(t+1)->b^1
//   ph3: A-h0(t+2)->b     (b's A region consumed at ph2, barrier-separated)
// vmcnt(2) at ph3: outstanding = 5 half-tiles (10 instrs/wave); keep 2 =>
// all 4 half-tiles of tile t+1 retired before closing barrier -> collective
// RAW guarantee for ph0(t+1)'s ds_reads.
// Swizzle: row-major [128][64] halves; thread t stages phys chunk (t&7) at
// row (t>>3) from global k-chunk (t&7)^(row&7); frag read at phys chunk
// (ks*4+quad)^(l16&7). Octet bank check: lanes 0-7 hit bank-quads
// 4*((q^l16)&7) mod 32 - all distinct -> conflict-free.
template <bool BF16OUT>
__global__ __launch_bounds__(512, 2) void gemm_bt(
    const unsigned short* __restrict__ A, const unsigned short* __restrict__ Bm,
    void* __restrict__ Cv, int M, int N, int K) {
  __shared__ unsigned short As[2 * 2 * 128 * 64];  // 64KB
  __shared__ unsigned short Bs[2 * 2 * 128 * 64];  // 64KB
  const int tid  = threadIdx.x;
  const int lane = tid & 63;
  const int w    = tid >> 6;           // 0..7
  const int quad = lane >> 4;
  const int l16  = lane & 15;
  const int bm = blockIdx.y * 256;
  const int bn = blockIdx.x * 256;
  const int wmh = w >> 2;              // A half this wave reads (0/1)
  const int wn  = (w & 3) * 64;
  const int hB  = (w & 3) >> 1;        // B half this wave reads

  // ---- staging thread mapping (pre-swizzled source, linear LDS dest) ----
  const int rr  = tid >> 3;                         // 0..63 (row within call)
  const int gch = ((tid & 7) ^ (rr & 7)) * 8;       // global k-chunk
  const unsigned short* gA = A + (size_t)(bm + rr) * K + gch;
  const unsigned short* gB = Bm + (size_t)(bn + rr) * K + gch;
  const size_t r64 = (size_t)64 * K;                // +64 rows

  // ---- fragment-read bases (u16 indices) ----
  const int cp0 = ((quad) ^ (l16 & 7)) * 8;         // ksub 0 phys chunk
  const int cp1 = ((4 + quad) ^ (l16 & 7)) * 8;     // ksub 1 phys chunk
  const int abase = wmh * 8192 + l16 * 64;
  const int bbase = hB * 8192 + ((w & 1) * 64 + l16) * 64;

  f32x4 acc[8][4];
#pragma unroll
  for (int f = 0; f < 8; f++)
#pragma unroll
    for (int c = 0; c < 4; c++)
#pragma unroll
      for (int r = 0; r < 4; r++) acc[f][c][r] = 0.f;

  // stage one half-tile (2 x async16): half h of K-tile tau into buffer buf
  auto stageA = [&](int tau, int h, int buf) {
    const unsigned short* s = gA + (size_t)(h * 2) * r64 + (size_t)tau * 64;
    unsigned short* d = As + buf * 16384 + h * 8192 + tid * 8;
    async16(s, d);
    async16(s + r64, d + 4096);
  };
  auto stageB = [&](int tau, int h, int buf) {
    const unsigned short* s = gB + (size_t)(h * 2) * r64 + (size_t)tau * 64;
    unsigned short* d = Bs + buf * 16384 + h * 8192 + tid * 8;
    async16(s, d);
    async16(s + r64, d + 4096);
  };

  // ---- prologue: tile 0 (4 half-tiles) + A-h0(tile 1); wait tile 0 ----
  stageA(0, 0, 0);
  stageA(0, 1, 0);
  stageB(0, 0, 0);
  stageB(0, 1, 0);
  stageA(1, 0, 1);
  asm volatile("s_waitcnt vmcnt(2)" ::: "memory");
  __builtin_amdgcn_s_barrier();

  const int KT = K >> 6;
  short8 a[4][2], b[2][2];
  for (int t = 0; t < KT; ++t) {
    const int cb = t & 1, nb = cb ^ 1;
    const int tn1 = (t + 1 < KT) ? t + 1 : KT - 1;   // clamped (dummy at end)
    const int tn2 = (t + 2 < KT) ? t + 2 : KT - 1;
    const unsigned short* Ab = As + cb * 16384 + abase;
    const unsigned short* Bb = Bs + cb * 16384 + bbase;

    // ---- phase 0: frags fh=0 x cols 0-1 ----
#pragma unroll
    for (int f = 0; f < 4; f++) {
      a[f][0] = *(const short8*)(Ab + f * 1024 + cp0);
      a[f][1] = *(const short8*)(Ab + f * 1024 + cp1);
    }
    b[0][0] = *(const short8*)(Bb + cp0);
    b[0][1] = *(const short8*)(Bb + cp1);
    b[1][0] = *(const short8*)(Bb + 1024 + cp0);
    b[1][1] = *(const short8*)(Bb + 1024 + cp1);
    stageA(tn1, 1, nb);
    __builtin_amdgcn_sched_barrier(0);
    __builtin_amdgcn_s_barrier();
    __builtin_amdgcn_s_setprio(1);
#pragma unroll
    for (int f = 0; f < 4; f++) {
      MFMA_B16(acc[f][0], a[f][0], b[0][0]);
      MFMA_B16(acc[f][0], a[f][1], b[0][1]);
      MFMA_B16(acc[f][1], a[f][0], b[1][0]);
      MFMA_B16(acc[f][1], a[f][1], b[1][1]);
    }
    __builtin_amdgcn_s_setprio(0);
    __builtin_amdgcn_s_barrier();

    // ---- phase 1: frags fh=0 x cols 2-3 (reuse a) ----
    b[0][0] = *(const short8*)(Bb + 2048 + cp0);
    b[0][1] = *(const short8*)(Bb + 2048 + cp1);
    b[1][0] = *(const short8*)(Bb + 3072 + cp0);
    b[1][1] = *(const short8*)(Bb + 3072 + cp1);
    stageB(tn1, 0, nb);
    __builtin_amdgcn_sched_barrier(0);
    __builtin_amdgcn_s_barrier();
    __builtin_amdgcn_s_setprio(1);
#pragma unroll
    for (int f = 0; f < 4; f++) {
      MFMA_B16(acc[f][2], a[f][0], b[0][0]);
      MFMA_B16(acc[f][2], a[f][1], b[0][1]);
      MFMA_B16(acc[f][3], a[f][0], b[1][0]);
      MFMA_B16(acc[f][3], a[f][1], b[1][1]);
    }
    __builtin_amdgcn_s_setprio(0);
    __builtin_amdgcn_s_barrier();

    // ---- phase 2: frags fh=1 x cols 0-1 ----
#pragma unroll
    for (int f = 0; f < 4; f++) {
      a[f][0] = *(const short8*)(Ab + 4096 + f * 1024 + cp0);
      a[f][1] = *(const short8*)(Ab + 4096 + f * 1024 + cp1);
    }
    b[0][0] = *(const short8*)(Bb + cp0);
    b[0][1] = *(const short8*)(Bb + cp1);
    b[1][0] = *(const short8*)(Bb + 1024 + cp0);
    b[1][1] = *(const short8*)(Bb + 1024 + cp1);
    stageB(tn1, 1, nb);
    __builtin_amdgcn_sched_barrier(0);
    __builtin_amdgcn_s_barrier();
    __builtin_amdgcn_s_setprio(1);
#pragma unroll
    for (int f = 0; f < 4; f++) {
      MFMA_B16(acc[4 + f][0], a[f][0], b[0][0]);
      MFMA_B16(acc[4 + f][0], a[f][1], b[0][1]);
      MFMA_B16(acc[4 + f][1], a[f][0], b[1][0]);
      MFMA_B16(acc[4 + f][1], a[f][1], b[1][1]);
    }
    __builtin_amdgcn_s_setprio(0);
    __builtin_amdgcn_s_barrier();

    // ---- phase 3: frags fh=1 x cols 2-3; stage A-h0(t+2); vmcnt ----
    b[0][0] = *(const short8*)(Bb + 2048 + cp0);
    b[0][1] = *(const short8*)(Bb + 2048 + cp1);
    b[1][0] = *(const short8*)(Bb + 3072 + cp0);
    b[1][1] = *(const short8*)(Bb + 3072 + cp1);
    stageA(tn2, 0, cb);
    asm volatile("s_waitcnt vmcnt(2)" ::: "memory");
    __builtin_amdgcn_sched_barrier(0);
    __builtin_amdgcn_s_barrier();
    __builtin_amdgcn_s_setprio(1);
#pragma unroll
    for (int f = 0; f < 4; f++) {
      MFMA_B16(acc[4 + f][2], a[f][0], b[0][0]);
      MFMA_B16(acc[4 + f][2], a[f][1], b[0][1]);
      MFMA_B16(acc[4 + f][3], a[f][0], b[1][0]);
      MFMA_B16(acc[4 + f][3], a[f][1], b[1][1]);
    }
    __builtin_amdgcn_s_setprio(0);
    __builtin_amdgcn_s_barrier();
  }
  // drain dead prefetch before endpgm
  asm volatile("s_waitcnt vmcnt(0)" ::: "memory");

  // C/D layout: col = lane&15, row = quad*4 + reg  [m89/m91 verified]
  const int crow0 = bm + wmh * 128 + quad * 4;
  const int ccol0 = bn + wn + l16;
  if constexpr (BF16OUT) {
    unsigned short* C = (unsigned short*)Cv;
#pragma unroll
    for (int f = 0; f < 8; f++)
#pragma unroll
      for (int c = 0; c < 4; c++)
#pragma unroll
        for (int r = 0; r < 4; r++)
          C[(size_t)(crow0 + f * 16 + r) * N + ccol0 + c * 16] = f2b(acc[f][c][r]);
  } else {
    float* C = (float*)Cv;
#pragma unroll
    for (int f = 0; f < 8; f++)
#pragma unroll
      for (int c = 0; c < 4; c++)
#pragma unroll
        for (int r = 0; r < 4; r++)
          C[(size_t)(crow0 + f * 16 + r) * N + ccol0 + c * 16] = acc[f][c][r];
  }
}

// ---------------- RoPE + staging-layout writes + cache scatter ---------------
// qkv arrives as bf16 (GEMM writes bf16 directly: halves qkv traffic).
// Q staging is pre-scaled by d^-0.5 * log2(e) so attention's S is already in
// the exp2 domain.
__global__ void rope_scatter(
    const unsigned short* __restrict__ qkv, const float* __restrict__ cosb,
    const float* __restrict__ sinb, const int* __restrict__ slots,
    unsigned short* __restrict__ qb, unsigned short* __restrict__ kb,
    unsigned short* __restrict__ vb, float* __restrict__ kco,
    float* __restrict__ vco) {
  const float sl2 = 0.08838834764831843f * 1.4426950408889634f;
  const int t = blockIdx.x;
  const int tid = threadIdx.x;
  const int b = t >> 10, s = t & 1023;
  const unsigned short* row = qkv + (size_t)t * QKVD;
  const float* cs = cosb + (size_t)t * 64;
  const float* sn = sinb + (size_t)t * 64;
  const int slot = slots[t];
  // Q: rope -> qb (B,H,S,D) bf16, pre-scaled
  for (int wk = tid; wk < H_ * 64; wk += 256) {
    int hh = wk >> 6, i = wk & 63;
    float x1 = b2f(row[hh * D_ + i]), x2 = b2f(row[hh * D_ + 64 + i]);
    float c = cs[i], sv = sn[i];
    size_t base = ((size_t)(b * H_ + hh) * S_ + s) * D_;
    qb[base + i]      = f2b((x1 * c - x2 * sv) * sl2);
    qb[base + 64 + i] = f2b((x1 * sv + x2 * c) * sl2);
  }
  // K: rope -> kb (B,KVH,S,D) bf16 + fp32 scatter to cache out
  for (int wk = tid; wk < KVH_ * 64; wk += 256) {
    int hh = wk >> 6, i = wk & 63;
    float x1 = b2f(row[H_ * D_ + hh * D_ + i]);
    float x2 = b2f(row[H_ * D_ + hh * D_ + 64 + i]);
    float c = cs[i], sv = sn[i];
    float o1 = x1 * c - x2 * sv, o2 = x1 * sv + x2 * c;
    size_t base = ((size_t)(b * KVH_ + hh) * S_ + s) * D_;
    kb[base + i] = f2b(o1);
    kb[base + 64 + i] = f2b(o2);
    size_t cb = ((size_t)slot * KVH_ + hh) * D_;
    kco[cb + i] = o1;
    kco[cb + 64 + i] = o2;
  }
  // V: copy -> vb (B,KVH,S,D) bf16 + fp32 scatter
  for (int wk = tid; wk < KVH_ * D_; wk += 256) {
    int hh = wk >> 7, i = wk & 127;
    unsigned short xv = row[H_ * D_ + KVH_ * D_ + hh * D_ + i];
    vb[((size_t)(b * KVH_ + hh) * S_ + s) * D_ + i] = xv;
    vco[((size_t)slot * KVH_ + hh) * D_ + i] = b2f(xv);
  }
}

// ---------------- V transpose: (BKV,S,D) -> (BKV,D,S) bf16 ----------------
__global__ void transpose_v(const unsigned short* __restrict__ vb,
                            unsigned short* __restrict__ vt) {
  __shared__ unsigned short tile[64][65];
  const int bid = blockIdx.x;
  const int dt = bid & 1, st = (bid >> 1) & 15, bk = bid >> 5;
  const int tid = threadIdx.x;
  const unsigned short* src = vb + ((size_t)bk * S_ + st * 64) * D_ + dt * 64;
#pragma unroll
  for (int k = 0; k < 16; k++) {
    int e = k * 256 + tid, r = e >> 6, c = e & 63;
    tile[r][c] = src[(size_t)r * D_ + c];
  }
  __syncthreads();
  unsigned short* dst = vt + ((size_t)bk * D_ + dt * 64) * S_ + st * 64;
#pragma unroll
  for (int k = 0; k < 16; k++) {
    int e = k * 256 + tid, r = e >> 6, c = e & 63;
    dst[(size_t)r * S_ + c] = tile[c][r];
  }
}

// ---------------- flash attention ----------------
// Block = 4 waves = one (b,h,64-row q-tile). Wave owns 16 q-rows.
// Row-sum l via MFMA against a ones-fragment (osum); diagonal mask is a
// scalar-guarded branch inside the single loop (no lambda / peel).
__global__ __launch_bounds__(256) void attn_fused(
    const unsigned short* __restrict__ qb, const unsigned short* __restrict__ kb,
    const unsigned short* __restrict__ vt, unsigned short* __restrict__ ob) {
  __shared__ unsigned short Ks[4 * 64 * 32];    // [kc][row][32] 16KB (also Q stage)
  __shared__ unsigned short Vs[2 * 128 * 32];   // [kc][d][32]   16KB
  __shared__ unsigned short Ps[4][2 * 16 * 32]; // per-wave [kc][row][32] 8KB
  const int tid = threadIdx.x;
  const int lane = tid & 63, w = tid >> 6;
  const int quad = lane >> 4, l16 = lane & 15;
  const int bidx = blockIdx.x;
  const int qt = 15 - (bidx & 15);  // heavy q-tiles dispatch first
  const int bh = bidx >> 4;
  const int h = bh & 31, b = bh >> 5;
  const int kvh = h >> 2;
  const int q0 = qt * 64;
  const unsigned short* qbase = qb + ((size_t)bh * S_ + q0) * D_;
  const unsigned short* kbase = kb + (size_t)(b * KVH_ + kvh) * S_ * D_;
  const unsigned short* vbase = vt + (size_t)(b * KVH_ + kvh) * D_ * S_;

  const int srow = tid >> 2;                               // 0..63
  const int scol = (((tid & 3) ^ ((tid >> 3) & 3)) * 8);   // staging swizzle
  const int qoff = (quad ^ ((l16 >> 1) & 3)) * 8;          // frag-read swizzle

  // ---- stage Q into Ks, chunked [kc][row][32] ----
#pragma unroll
  for (int i = 0; i < 4; i++)
    async16(qbase + (size_t)srow * D_ + i * 32 + scol, (unsigned short*)Ks + i * 2048 + tid * 8);
  __syncthreads();
  short8 qf[4];
#pragma unroll
  for (int kc = 0; kc < 4; kc++)
    qf[kc] = *(const short8*)(Ks + (kc * 64 + w * 16 + l16) * 32 + qoff);

  // ones B-fragment: B[n][k]=1 for n==0 (n = l16), else 0
  short8 of;
  {
    unsigned short ov = (l16 == 0) ? (unsigned short)0x3F80 : (unsigned short)0;
#pragma unroll
    for (int j = 0; j < 8; j++) of[j] = (short)ov;
  }

  f32x4 oac[8];
  f32x4 osum;
#pragma unroll
  for (int n = 0; n < 8; n++)
#pragma unroll
    for (int r = 0; r < 4; r++) oac[n][r] = 0.f;
#pragma unroll
  for (int r = 0; r < 4; r++) osum[r] = 0.f;
  float m_run[4] = {-3.0e38f, -3.0e38f, -3.0e38f, -3.0e38f};

  unsigned short* psw = &Ps[w][0];
  const int qrow = q0 + w * 16 + quad * 4;  // + r

  for (int jt = 0; jt <= qt; jt++) {
    __syncthreads();  // prior iter LDS reads (and qf reads) complete
    const int j0 = jt * 64;
#pragma unroll
    for (int i = 0; i < 4; i++)
      async16(kbase + (size_t)(j0 + srow) * D_ + i * 32 + scol,
              (unsigned short*)Ks + i * 2048 + tid * 8);
#pragma unroll
    for (int i = 0; i < 4; i++) {
      int kc = i >> 1;
      int d = (i & 1) * 64 + srow;
      async16(vbase + (size_t)d * S_ + j0 + kc * 32 + scol,
              (unsigned short*)Vs + i * 2048 + tid * 8);
    }
    __syncthreads();

    // ---- S = Q K^T (already in exp2 domain; Q pre-scaled) ----
    f32x4 sac[4];
#pragma unroll
    for (int t = 0; t < 4; t++)
#pragma unroll
      for (int r = 0; r < 4; r++) sac[t][r] = 0.f;
#pragma unroll
    for (int t = 0; t < 4; t++)
#pragma unroll
      for (int kc = 0; kc < 4; kc++)
        sac[t] = __builtin_amdgcn_mfma_f32_16x16x32_bf16(
            qf[kc], *(const short8*)(Ks + (kc * 64 + t * 16 + l16) * 32 + qoff),
            sac[t], 0, 0, 0);

    if (jt == qt) {  // scalar-uniform branch: diagonal tile causal mask
#pragma unroll
      for (int t = 0; t < 4; t++) {
        const int kcol = j0 + t * 16 + l16;
#pragma unroll
        for (int r = 0; r < 4; r++)
          if (kcol > qrow + r) sac[t][r] = -3.0e38f;
      }
    }
    // ---- row max (16-lane butterfly) ----
    float mx[4];
#pragma unroll
    for (int r = 0; r < 4; r++)
      mx[r] = fmaxf(fmaxf(sac[0][r], sac[1][r]), fmaxf(sac[2][r], sac[3][r]));
#pragma unroll
    for (int off = 1; off < 16; off <<= 1)
#pragma unroll
      for (int r = 0; r < 4; r++) mx[r] = fmaxf(mx[r], __shfl_xor(mx[r], off));
    float alpha[4];
#pragma unroll
    for (int r = 0; r < 4; r++) {
      float mn = fmaxf(m_run[r], mx[r]);
      alpha[r] = exp2f(m_run[r] - mn);
      m_run[r] = mn;
    }
    // ---- P = exp2(S-m) -> LDS (C-layout -> A-layout), swizzled ----
#pragma unroll
    for (int t = 0; t < 4; t++)
#pragma unroll
      for (int r = 0; r < 4; r++) {
        float p = exp2f(sac[t][r] - m_run[r]);
        int prow = quad * 4 + r;
        int chunk = (((t & 1) * 2 + (l16 >> 3)) ^ ((prow >> 1) & 3));
        psw[(t >> 1) * 512 + prow * 32 + chunk * 8 + (l16 & 7)] = f2b(p);
      }
    // ---- rescale accumulators (osum carries the running row-sum l) ----
#pragma unroll
    for (int r = 0; r < 4; r++) osum[r] *= alpha[r];
#pragma unroll
    for (int n = 0; n < 8; n++)
#pragma unroll
      for (int r = 0; r < 4; r++) oac[n][r] *= alpha[r];
    // ---- O += P V ; l += P . 1  (wave-local Ps, lgkmcnt-ordered) ----
#pragma unroll
    for (int kc = 0; kc < 2; kc++) {
      short8 pf = *(const short8*)(psw + kc * 512 + l16 * 32 + qoff);
      osum = __builtin_amdgcn_mfma_f32_16x16x32_bf16(pf, of, osum, 0, 0, 0);
#pragma unroll
      for (int n = 0; n < 8; n++)
        oac[n] = __builtin_amdgcn_mfma_f32_16x16x32_bf16(
            pf, *(const short8*)(Vs + (kc * 128 + n * 16 + l16) * 32 + qoff),
            oac[n], 0, 0, 0);
    }
  }

  // ---- epilogue: l lives in col 0 of osum (lane quad*16). normalize. ----
  float inv[4];
#pragma unroll
  for (int r = 0; r < 4; r++) {
    float l = __shfl(osum[r], lane & 48, 64);
    inv[r] = 1.0f / l;
  }
  const size_t trow = (size_t)(b * S_ + q0 + w * 16 + quad * 4);
#pragma unroll
  for (int n = 0; n < 8; n++)
#pragma unroll
    for (int r = 0; r < 4; r++)
      ob[(trow + r) * (size_t)(H_ * D_) + h * D_ + n * 16 + l16] =
          f2b(oac[n][r] * inv[r]);
}

// ---------------- launch ----------------
extern "C" void kernel_launch(void* const* d_in, const int* in_sizes, int n_in,
                              void* d_out, int out_size, void* d_ws, size_t ws_size,
                              hipStream_t stream) {
  const float* hidden = (const float*)d_in[0];
  const float* cosb   = (const float*)d_in[1];
  const float* sinb   = (const float*)d_in[2];
  const float* wqkv   = (const float*)d_in[3];
  const float* wo     = (const float*)d_in[4];
  const float* kc_in  = (const float*)d_in[5];
  const float* vc_in  = (const float*)d_in[6];
  const int*   slots  = (const int*)d_in[7];

  float* out    = (float*)d_out;                       // T*HID
  float* kc_out = out + (size_t)T_ * HID;              // NSLOT*KVH*D
  float* vc_out = kc_out + (size_t)NSLOT * KVH_ * D_;

  // workspace carve-up
  char* ws = (char*)d_ws;
  unsigned short* hb    = (unsigned short*)ws; ws += (size_t)T_ * HID * 2;
  unsigned short* wqkvb = (unsigned short*)ws; ws += (size_t)QKVD * HID * 2;
  unsigned short* wob   = (unsigned short*)ws; ws += (size_t)HID * HID * 2;
  unsigned short* qkv   = (unsigned short*)ws; ws += (size_t)T_ * QKVD * 2;
  unsigned short* qb    = (unsigned short*)ws; ws += (size_t)T_ * H_ * D_ * 2;
  unsigned short* kb    = (unsigned short*)ws; ws += (size_t)T_ * KVH_ * D_ * 2;
  unsigned short* vb    = (unsigned short*)ws; ws += (size_t)T_ * KVH_ * D_ * 2;
  unsigned short* vt    = (unsigned short*)ws; ws += (size_t)T_ * KVH_ * D_ * 2;
  unsigned short* ob    = (unsigned short*)ws;

  // cache passthrough (scatter overwrites first T slots)
  const size_t cache_bytes = (size_t)NSLOT * KVH_ * D_ * 4;
  hipMemcpyAsync(kc_out, kc_in, cache_bytes, hipMemcpyDeviceToDevice, stream);
  hipMemcpyAsync(vc_out, vc_in, cache_bytes, hipMemcpyDeviceToDevice, stream);

  conv_bf16<<<(T_ * HID / 4) / 256, 256, 0, stream>>>(hidden, hb, T_ * HID / 4);
  conv_bf16<<<(QKVD * HID / 4) / 256, 256, 0, stream>>>(wqkv, wqkvb, QKVD * HID / 4);
  conv_bf16<<<(HID * HID / 4) / 256, 256, 0, stream>>>(wo, wob, HID * HID / 4);

  dim3 g1(QKVD / 256, T_ / 256);
  gemm_bt<true><<<g1, 512, 0, stream>>>(hb, wqkvb, qkv, T_, QKVD, HID);

  rope_scatter<<<T_, 256, 0, stream>>>(qkv, cosb, sinb, slots, qb, kb, vb, kc_out, vc_out);

  transpose_v<<<B_ * KVH_ * 16 * 2, 256, 0, stream>>>(vb, vt);

  attn_fused<<<B_ * H_ * (S_ / 64), 256, 0, stream>>>(qb, kb, vt, ob);

  dim3 g2(HID / 256, T_ / 256);
  gemm_bt<false><<<g2, 512, 0, stream>>>(ob, wob, out, T_, HID, HID);
}

// Round 3
// 918.385 us; speedup vs baseline: 1.0771x; 1.0771x over previous
//
#include <hip/hip_runtime.h>
#include <hip/hip_bf16.h>

// ---------------- problem constants ----------------
#define B_    4
#define S_    1024
#define HID   4096
#define H_    32
#define KVH_  8
#define D_    128
#define T_    (B_ * S_)        // 4096
#define QKVD  (H_ * D_ + 2 * KVH_ * D_)  // 6144
#define NSLOT 8192

typedef __attribute__((ext_vector_type(8))) short short8;   // 8 bf16 = 4 VGPRs
typedef __attribute__((ext_vector_type(4))) float f32x4;

#define MFMA_B16(d, x, y) \
  d = __builtin_amdgcn_mfma_f32_16x16x32_bf16(x, y, d, 0, 0, 0)

__device__ __forceinline__ unsigned short f2b(float f) {
  union { __hip_bfloat16 h; unsigned short u; } c;
  c.h = __float2bfloat16(f);
  return c.u;
}
__device__ __forceinline__ float b2f(unsigned short u) {
  union { unsigned int i; float f; } c;
  c.i = ((unsigned int)u) << 16;
  return c.f;
}

// async global->LDS 16B. LDS dest must be wave-uniform base + lane*16.
__device__ __forceinline__ void async16(const void* g, void* l) {
  __builtin_amdgcn_global_load_lds(
      (const __attribute__((address_space(1))) unsigned int*)g,
      (__attribute__((address_space(3))) unsigned int*)l,
      16, 0, 0);
}

// ---------------- fp32 -> bf16 convert ----------------
__global__ void conv_bf16(const float* __restrict__ src,
                          unsigned short* __restrict__ dst, int n4) {
  int i = blockIdx.x * 256 + threadIdx.x;
  if (i >= n4) return;
  float4 v = reinterpret_cast<const float4*>(src)[i];
  ushort4 o;
  o.x = f2b(v.x); o.y = f2b(v.y); o.z = f2b(v.z); o.w = f2b(v.w);
  reinterpret_cast<ushort4*>(dst)[i] = o;
}

// ---------------- GEMM: C(M,N) = A(M,K)bf16 * B(N,K)bf16 ^T ------------------
// 256x256 tile, BK=64, 8 waves (2M x 4N), 512 thr, 4 phases/K-tile.
// Round-3 deltas vs round-2 (same sync structure, verified twice):
//  (a) B frags held in regs across the whole K-tile: 24 ds_read_b128/wave/K-tile
//      (the minimum), was 32 -> -25% LDS read traffic.
//  (b) sched_barrier(0) pins removed (not in m201 template) -> compiler free to
//      fine-schedule lgkmcnt and slip waves for read||MFMA overlap.
// Reads per phase: 12 / 4 / 8 / 0. 16 MFMA per phase. ONE vmcnt(2) per K-tile.
//
// LDS: As/Bs = [buf2][half2][128 rows][64 k] bf16, 64KB each, 128KB total.
// Stage slots (tile t in buf cb, nb=cb^1):
//   ph0: A-h1(t+1)->nb  (nb's A-h1 last read at ph2 of t-1, barrier-separated)
//   ph1: B-h0(t+1)->nb  (nb's B reads finished by ph1 of t-1)
//   ph2: B-h1(t+1)->nb
//   ph3: A-h0(t+2)->cb  (cb's A-h0 fully read by ph2 of t, barrier-separated)
// vmcnt(2) at ph3: outstanding = 10 instrs (5 half-tiles); keep 2 (A-h0(t+2))
// => all 4 half-tiles of tile t+1 resident before the closing barrier.
// Swizzle: thread t stages phys chunk (t&7) at row (t>>3) from global k-chunk
// (t&7)^(row&7); frag read at phys chunk (ks*4+quad)^(l16&7). Bank-check:
// conflict-free (SQ_LDS_BANK_CONFLICT==0 measured rounds 1-2).
template <bool BF16OUT>
__global__ __launch_bounds__(512, 2) void gemm_bt(
    const unsigned short* __restrict__ A, const unsigned short* __restrict__ Bm,
    void* __restrict__ Cv, int M, int N, int K) {
  __shared__ unsigned short As[2 * 2 * 128 * 64];  // 64KB
  __shared__ unsigned short Bs[2 * 2 * 128 * 64];  // 64KB
  const int tid  = threadIdx.x;
  const int lane = tid & 63;
  const int w    = tid >> 6;           // 0..7
  const int quad = lane >> 4;
  const int l16  = lane & 15;
  const int bm = blockIdx.y * 256;
  const int bn = blockIdx.x * 256;
  const int wmh = w >> 2;              // A half this wave reads (0/1)
  const int wn  = (w & 3) * 64;
  const int hB  = (w & 3) >> 1;        // B half this wave reads

  // ---- staging thread mapping (pre-swizzled source, linear LDS dest) ----
  const int rr  = tid >> 3;                         // 0..63 (row within call)
  const int gch = ((tid & 7) ^ (rr & 7)) * 8;       // global k-chunk
  const unsigned short* gA = A + (size_t)(bm + rr) * K + gch;
  const unsigned short* gB = Bm + (size_t)(bn + rr) * K + gch;
  const size_t r64 = (size_t)64 * K;                // +64 rows

  // ---- fragment-read bases (u16 indices) ----
  const int cp0 = ((quad) ^ (l16 & 7)) * 8;         // ksub 0 phys chunk
  const int cp1 = ((4 + quad) ^ (l16 & 7)) * 8;     // ksub 1 phys chunk
  const int abase = wmh * 8192 + l16 * 64;
  const int bbase = hB * 8192 + ((w & 1) * 64 + l16) * 64;

  f32x4 acc[8][4];
#pragma unroll
  for (int f = 0; f < 8; f++)
#pragma unroll
    for (int c = 0; c < 4; c++)
#pragma unroll
      for (int r = 0; r < 4; r++) acc[f][c][r] = 0.f;

  // stage one half-tile (2 x async16): half h of K-tile tau into buffer buf
  auto stageA = [&](int tau, int h, int buf) {
    const unsigned short* s = gA + (size_t)(h * 2) * r64 + (size_t)tau * 64;
    unsigned short* d = As + buf * 16384 + h * 8192 + tid * 8;
    async16(s, d);
    async16(s + r64, d + 4096);
  };
  auto stageB = [&](int tau, int h, int buf) {
    const unsigned short* s = gB + (size_t)(h * 2) * r64 + (size_t)tau * 64;
    unsigned short* d = Bs + buf * 16384 + h * 8192 + tid * 8;
    async16(s, d);
    async16(s + r64, d + 4096);
  };

  // ---- prologue: tile 0 (4 half-tiles) + A-h0(tile 1); wait tile 0 ----
  stageA(0, 0, 0);
  stageA(0, 1, 0);
  stageB(0, 0, 0);
  stageB(0, 1, 0);
  stageA(1, 0, 1);
  asm volatile("s_waitcnt vmcnt(2)" ::: "memory");
  __builtin_amdgcn_s_barrier();

  const int KT = K >> 6;
  short8 a[4][2], b[4][2];
  for (int t = 0; t < KT; ++t) {
    const int cb = t & 1, nb = cb ^ 1;
    const int tn1 = (t + 1 < KT) ? t + 1 : KT - 1;   // clamped (dummy at end)
    const int tn2 = (t + 2 < KT) ? t + 2 : KT - 1;
    const unsigned short* Ab = As + cb * 16384 + abase;
    const unsigned short* Bb = Bs + cb * 16384 + bbase;

    // ---- phase 0: read a(fh0) + b(cols 0-1); MFMA fh0 x cols 0-1 ----
#pragma unroll
    for (int f = 0; f < 4; f++) {
      a[f][0] = *(const short8*)(Ab + f * 1024 + cp0);
      a[f][1] = *(const short8*)(Ab + f * 1024 + cp1);
    }
    b[0][0] = *(const short8*)(Bb + cp0);
    b[0][1] = *(const short8*)(Bb + cp1);
    b[1][0] = *(const short8*)(Bb + 1024 + cp0);
    b[1][1] = *(const short8*)(Bb + 1024 + cp1);
    stageA(tn1, 1, nb);
    __builtin_amdgcn_s_barrier();
    __builtin_amdgcn_s_setprio(1);
#pragma unroll
    for (int f = 0; f < 4; f++) {
      MFMA_B16(acc[f][0], a[f][0], b[0][0]);
      MFMA_B16(acc[f][0], a[f][1], b[0][1]);
      MFMA_B16(acc[f][1], a[f][0], b[1][0]);
      MFMA_B16(acc[f][1], a[f][1], b[1][1]);
    }
    __builtin_amdgcn_s_setprio(0);
    __builtin_amdgcn_s_barrier();

    // ---- phase 1: read b(cols 2-3); MFMA fh0 x cols 2-3 ----
    b[2][0] = *(const short8*)(Bb + 2048 + cp0);
    b[2][1] = *(const short8*)(Bb + 2048 + cp1);
    b[3][0] = *(const short8*)(Bb + 3072 + cp0);
    b[3][1] = *(const short8*)(Bb + 3072 + cp1);
    stageB(tn1, 0, nb);
    __builtin_amdgcn_s_barrier();
    __builtin_amdgcn_s_setprio(1);
#pragma unroll
    for (int f = 0; f < 4; f++) {
      MFMA_B16(acc[f][2], a[f][0], b[2][0]);
      MFMA_B16(acc[f][2], a[f][1], b[2][1]);
      MFMA_B16(acc[f][3], a[f][0], b[3][0]);
      MFMA_B16(acc[f][3], a[f][1], b[3][1]);
    }
    __builtin_amdgcn_s_setprio(0);
    __builtin_amdgcn_s_barrier();

    // ---- phase 2: read a(fh1); MFMA fh1 x cols 0-1 (b01 live in regs) ----
#pragma unroll
    for (int f = 0; f < 4; f++) {
      a[f][0] = *(const short8*)(Ab + 4096 + f * 1024 + cp0);
      a[f][1] = *(const short8*)(Ab + 4096 + f * 1024 + cp1);
    }
    stageB(tn1, 1, nb);
    __builtin_amdgcn_s_barrier();
    __builtin_amdgcn_s_setprio(1);
#pragma unroll
    for (int f = 0; f < 4; f++) {
      MFMA_B16(acc[4 + f][0], a[f][0], b[0][0]);
      MFMA_B16(acc[4 + f][0], a[f][1], b[0][1]);
      MFMA_B16(acc[4 + f][1], a[f][0], b[1][0]);
      MFMA_B16(acc[4 + f][1], a[f][1], b[1][1]);
    }
    __builtin_amdgcn_s_setprio(0);
    __builtin_amdgcn_s_barrier();

    // ---- phase 3: no reads; stage A-h0(t+2); vmcnt; MFMA fh1 x cols 2-3 ----
    stageA(tn2, 0, cb);
    asm volatile("s_waitcnt vmcnt(2)" ::: "memory");
    __builtin_amdgcn_s_barrier();
    __builtin_amdgcn_s_setprio(1);
#pragma unroll
    for (int f = 0; f < 4; f++) {
      MFMA_B16(acc[4 + f][2], a[f][0], b[2][0]);
      MFMA_B16(acc[4 + f][2], a[f][1], b[2][1]);
      MFMA_B16(acc[4 + f][3], a[f][0], b[3][0]);
      MFMA_B16(acc[4 + f][3], a[f][1], b[3][1]);
    }
    __builtin_amdgcn_s_setprio(0);
    __builtin_amdgcn_s_barrier();
  }
  // drain dead prefetch before endpgm
  asm volatile("s_waitcnt vmcnt(0)" ::: "memory");

  // C/D layout: col = lane&15, row = quad*4 + reg  [m89/m91 verified]
  const int crow0 = bm + wmh * 128 + quad * 4;
  const int ccol0 = bn + wn + l16;
  if constexpr (BF16OUT) {
    unsigned short* C = (unsigned short*)Cv;
#pragma unroll
    for (int f = 0; f < 8; f++)
#pragma unroll
      for (int c = 0; c < 4; c++)
#pragma unroll
        for (int r = 0; r < 4; r++)
          C[(size_t)(crow0 + f * 16 + r) * N + ccol0 + c * 16] = f2b(acc[f][c][r]);
  } else {
    float* C = (float*)Cv;
#pragma unroll
    for (int f = 0; f < 8; f++)
#pragma unroll
      for (int c = 0; c < 4; c++)
#pragma unroll
        for (int r = 0; r < 4; r++)
          C[(size_t)(crow0 + f * 16 + r) * N + ccol0 + c * 16] = acc[f][c][r];
  }
}

// ---------------- RoPE + staging-layout writes + cache scatter ---------------
// qkv arrives as bf16 (GEMM writes bf16 directly: halves qkv traffic).
// Q staging is pre-scaled by d^-0.5 * log2(e) so attention's S is already in
// the exp2 domain.
__global__ void rope_scatter(
    const unsigned short* __restrict__ qkv, const float* __restrict__ cosb,
    const float* __restrict__ sinb, const int* __restrict__ slots,
    unsigned short* __restrict__ qb, unsigned short* __restrict__ kb,
    unsigned short* __restrict__ vb, float* __restrict__ kco,
    float* __restrict__ vco) {
  const float sl2 = 0.08838834764831843f * 1.4426950408889634f;
  const int t = blockIdx.x;
  const int tid = threadIdx.x;
  const int b = t >> 10, s = t & 1023;
  const unsigned short* row = qkv + (size_t)t * QKVD;
  const float* cs = cosb + (size_t)t * 64;
  const float* sn = sinb + (size_t)t * 64;
  const int slot = slots[t];
  // Q: rope -> qb (B,H,S,D) bf16, pre-scaled
  for (int wk = tid; wk < H_ * 64; wk += 256) {
    int hh = wk >> 6, i = wk & 63;
    float x1 = b2f(row[hh * D_ + i]), x2 = b2f(row[hh * D_ + 64 + i]);
    float c = cs[i], sv = sn[i];
    size_t base = ((size_t)(b * H_ + hh) * S_ + s) * D_;
    qb[base + i]      = f2b((x1 * c - x2 * sv) * sl2);
    qb[base + 64 + i] = f2b((x1 * sv + x2 * c) * sl2);
  }
  // K: rope -> kb (B,KVH,S,D) bf16 + fp32 scatter to cache out
  for (int wk = tid; wk < KVH_ * 64; wk += 256) {
    int hh = wk >> 6, i = wk & 63;
    float x1 = b2f(row[H_ * D_ + hh * D_ + i]);
    float x2 = b2f(row[H_ * D_ + hh * D_ + 64 + i]);
    float c = cs[i], sv = sn[i];
    float o1 = x1 * c - x2 * sv, o2 = x1 * sv + x2 * c;
    size_t base = ((size_t)(b * KVH_ + hh) * S_ + s) * D_;
    kb[base + i] = f2b(o1);
    kb[base + 64 + i] = f2b(o2);
    size_t cb = ((size_t)slot * KVH_ + hh) * D_;
    kco[cb + i] = o1;
    kco[cb + 64 + i] = o2;
  }
  // V: copy -> vb (B,KVH,S,D) bf16 + fp32 scatter
  for (int wk = tid; wk < KVH_ * D_; wk += 256) {
    int hh = wk >> 7, i = wk & 127;
    unsigned short xv = row[H_ * D_ + KVH_ * D_ + hh * D_ + i];
    vb[((size_t)(b * KVH_ + hh) * S_ + s) * D_ + i] = xv;
    vco[((size_t)slot * KVH_ + hh) * D_ + i] = b2f(xv);
  }
}

// ---------------- V transpose: (BKV,S,D) -> (BKV,D,S) bf16 ----------------
__global__ void transpose_v(const unsigned short* __restrict__ vb,
                            unsigned short* __restrict__ vt) {
  __shared__ unsigned short tile[64][65];
  const int bid = blockIdx.x;
  const int dt = bid & 1, st = (bid >> 1) & 15, bk = bid >> 5;
  const int tid = threadIdx.x;
  const unsigned short* src = vb + ((size_t)bk * S_ + st * 64) * D_ + dt * 64;
#pragma unroll
  for (int k = 0; k < 16; k++) {
    int e = k * 256 + tid, r = e >> 6, c = e & 63;
    tile[r][c] = src[(size_t)r * D_ + c];
  }
  __syncthreads();
  unsigned short* dst = vt + ((size_t)bk * D_ + dt * 64) * S_ + st * 64;
#pragma unroll
  for (int k = 0; k < 16; k++) {
    int e = k * 256 + tid, r = e >> 6, c = e & 63;
    dst[(size_t)r * S_ + c] = tile[c][r];
  }
}

// ---------------- flash attention ----------------
// Block = 4 waves = one (b,h,64-row q-tile). Wave owns 16 q-rows.
// Row-sum l via MFMA against a ones-fragment (osum); diagonal mask is a
// scalar-guarded branch inside the single loop (no lambda / peel).
__global__ __launch_bounds__(256) void attn_fused(
    const unsigned short* __restrict__ qb, const unsigned short* __restrict__ kb,
    const unsigned short* __restrict__ vt, unsigned short* __restrict__ ob) {
  __shared__ unsigned short Ks[4 * 64 * 32];    // [kc][row][32] 16KB (also Q stage)
  __shared__ unsigned short Vs[2 * 128 * 32];   // [kc][d][32]   16KB
  __shared__ unsigned short Ps[4][2 * 16 * 32]; // per-wave [kc][row][32] 8KB
  const int tid = threadIdx.x;
  const int lane = tid & 63, w = tid >> 6;
  const int quad = lane >> 4, l16 = lane & 15;
  const int bidx = blockIdx.x;
  const int qt = 15 - (bidx & 15);  // heavy q-tiles dispatch first
  const int bh = bidx >> 4;
  const int h = bh & 31, b = bh >> 5;
  const int kvh = h >> 2;
  const int q0 = qt * 64;
  const unsigned short* qbase = qb + ((size_t)bh * S_ + q0) * D_;
  const unsigned short* kbase = kb + (size_t)(b * KVH_ + kvh) * S_ * D_;
  const unsigned short* vbase = vt + (size_t)(b * KVH_ + kvh) * D_ * S_;

  const int srow = tid >> 2;                               // 0..63
  const int scol = (((tid & 3) ^ ((tid >> 3) & 3)) * 8);   // staging swizzle
  const int qoff = (quad ^ ((l16 >> 1) & 3)) * 8;          // frag-read swizzle

  // ---- stage Q into Ks, chunked [kc][row][32] ----
#pragma unroll
  for (int i = 0; i < 4; i++)
    async16(qbase + (size_t)srow * D_ + i * 32 + scol, (unsigned short*)Ks + i * 2048 + tid * 8);
  __syncthreads();
  short8 qf[4];
#pragma unroll
  for (int kc = 0; kc < 4; kc++)
    qf[kc] = *(const short8*)(Ks + (kc * 64 + w * 16 + l16) * 32 + qoff);

  // ones B-fragment: B[n][k]=1 for n==0 (n = l16), else 0
  short8 of;
  {
    unsigned short ov = (l16 == 0) ? (unsigned short)0x3F80 : (unsigned short)0;
#pragma unroll
    for (int j = 0; j < 8; j++) of[j] = (short)ov;
  }

  f32x4 oac[8];
  f32x4 osum;
#pragma unroll
  for (int n = 0; n < 8; n++)
#pragma unroll
    for (int r = 0; r < 4; r++) oac[n][r] = 0.f;
#pragma unroll
  for (int r = 0; r < 4; r++) osum[r] = 0.f;
  float m_run[4] = {-3.0e38f, -3.0e38f, -3.0e38f, -3.0e38f};

  unsigned short* psw = &Ps[w][0];
  const int qrow = q0 + w * 16 + quad * 4;  // + r

  for (int jt = 0; jt <= qt; jt++) {
    __syncthreads();  // prior iter LDS reads (and qf reads) complete
    const int j0 = jt * 64;
#pragma unroll
    for (int i = 0; i < 4; i++)
      async16(kbase + (size_t)(j0 + srow) * D_ + i * 32 + scol,
              (unsigned short*)Ks + i * 2048 + tid * 8);
#pragma unroll
    for (int i = 0; i < 4; i++) {
      int kc = i >> 1;
      int d = (i & 1) * 64 + srow;
      async16(vbase + (size_t)d * S_ + j0 + kc * 32 + scol,
              (unsigned short*)Vs + i * 2048 + tid * 8);
    }
    __syncthreads();

    // ---- S = Q K^T (already in exp2 domain; Q pre-scaled) ----
    f32x4 sac[4];
#pragma unroll
    for (int t = 0; t < 4; t++)
#pragma unroll
      for (int r = 0; r < 4; r++) sac[t][r] = 0.f;
#pragma unroll
    for (int t = 0; t < 4; t++)
#pragma unroll
      for (int kc = 0; kc < 4; kc++)
        sac[t] = __builtin_amdgcn_mfma_f32_16x16x32_bf16(
            qf[kc], *(const short8*)(Ks + (kc * 64 + t * 16 + l16) * 32 + qoff),
            sac[t], 0, 0, 0);

    if (jt == qt) {  // scalar-uniform branch: diagonal tile causal mask
#pragma unroll
      for (int t = 0; t < 4; t++) {
        const int kcol = j0 + t * 16 + l16;
#pragma unroll
        for (int r = 0; r < 4; r++)
          if (kcol > qrow + r) sac[t][r] = -3.0e38f;
      }
    }
    // ---- row max (16-lane butterfly) ----
    float mx[4];
#pragma unroll
    for (int r = 0; r < 4; r++)
      mx[r] = fmaxf(fmaxf(sac[0][r], sac[1][r]), fmaxf(sac[2][r], sac[3][r]));
#pragma unroll
    for (int off = 1; off < 16; off <<= 1)
#pragma unroll
      for (int r = 0; r < 4; r++) mx[r] = fmaxf(mx[r], __shfl_xor(mx[r], off));
    float alpha[4];
#pragma unroll
    for (int r = 0; r < 4; r++) {
      float mn = fmaxf(m_run[r], mx[r]);
      alpha[r] = exp2f(m_run[r] - mn);
      m_run[r] = mn;
    }
    // ---- P = exp2(S-m) -> LDS (C-layout -> A-layout), swizzled ----
#pragma unroll
    for (int t = 0; t < 4; t++)
#pragma unroll
      for (int r = 0; r < 4; r++) {
        float p = exp2f(sac[t][r] - m_run[r]);
        int prow = quad * 4 + r;
        int chunk = (((t & 1) * 2 + (l16 >> 3)) ^ ((prow >> 1) & 3));
        psw[(t >> 1) * 512 + prow * 32 + chunk * 8 + (l16 & 7)] = f2b(p);
      }
    // ---- rescale accumulators (osum carries the running row-sum l) ----
#pragma unroll
    for (int r = 0; r < 4; r++) osum[r] *= alpha[r];
#pragma unroll
    for (int n = 0; n < 8; n++)
#pragma unroll
      for (int r = 0; r < 4; r++) oac[n][r] *= alpha[r];
    // ---- O += P V ; l += P . 1  (wave-local Ps, lgkmcnt-ordered) ----
#pragma unroll
    for (int kc = 0; kc < 2; kc++) {
      short8 pf = *(const short8*)(psw + kc * 512 + l16 * 32 + qoff);
      osum = __builtin_amdgcn_mfma_f32_16x16x32_bf16(pf, of, osum, 0, 0, 0);
#pragma unroll
      for (int n = 0; n < 8; n++)
        oac[n] = __builtin_amdgcn_mfma_f32_16x16x32_bf16(
            pf, *(const short8*)(Vs + (kc * 128 + n * 16 + l16) * 32 + qoff),
            oac[n], 0, 0, 0);
    }
  }

  // ---- epilogue: l lives in col 0 of osum (lane quad*16). normalize. ----
  float inv[4];
#pragma unroll
  for (int r = 0; r < 4; r++) {
    float l = __shfl(osum[r], lane & 48, 64);
    inv[r] = 1.0f / l;
  }
  const size_t trow = (size_t)(b * S_ + q0 + w * 16 + quad * 4);
#pragma unroll
  for (int n = 0; n < 8; n++)
#pragma unroll
    for (int r = 0; r < 4; r++)
      ob[(trow + r) * (size_t)(H_ * D_) + h * D_ + n * 16 + l16] =
          f2b(oac[n][r] * inv[r]);
}

// ---------------- launch ----------------
extern "C" void kernel_launch(void* const* d_in, const int* in_sizes, int n_in,
                              void* d_out, int out_size, void* d_ws, size_t ws_size,
                              hipStream_t stream) {
  const float* hidden = (const float*)d_in[0];
  const float* cosb   = (const float*)d_in[1];
  const float* sinb   = (const float*)d_in[2];
  const float* wqkv   = (const float*)d_in[3];
  const float* wo     = (const float*)d_in[4];
  const float* kc_in  = (const float*)d_in[5];
  const float* vc_in  = (const float*)d_in[6];
  const int*   slots  = (const int*)d_in[7];

  float* out    = (float*)d_out;                       // T*HID
  float* kc_out = out + (size_t)T_ * HID;              // NSLOT*KVH*D
  float* vc_out = kc_out + (size_t)NSLOT * KVH_ * D_;

  // workspace carve-up
  char* ws = (char*)d_ws;
  unsigned short* hb    = (unsigned short*)ws; ws += (size_t)T_ * HID * 2;
  unsigned short* wqkvb = (unsigned short*)ws; ws += (size_t)QKVD * HID * 2;
  unsigned short* wob   = (unsigned short*)ws; ws += (size_t)HID * HID * 2;
  unsigned short* qkv   = (unsigned short*)ws; ws += (size_t)T_ * QKVD * 2;
  unsigned short* qb    = (unsigned short*)ws; ws += (size_t)T_ * H_ * D_ * 2;
  unsigned short* kb    = (unsigned short*)ws; ws += (size_t)T_ * KVH_ * D_ * 2;
  unsigned short* vb    = (unsigned short*)ws; ws += (size_t)T_ * KVH_ * D_ * 2;
  unsigned short* vt    = (unsigned short*)ws; ws += (size_t)T_ * KVH_ * D_ * 2;
  unsigned short* ob    = (unsigned short*)ws;

  // cache passthrough (scatter overwrites first T slots)
  const size_t cache_bytes = (size_t)NSLOT * KVH_ * D_ * 4;
  hipMemcpyAsync(kc_out, kc_in, cache_bytes, hipMemcpyDeviceToDevice, stream);
  hipMemcpyAsync(vc_out, vc_in, cache_bytes, hipMemcpyDeviceToDevice, stream);

  conv_bf16<<<(T_ * HID / 4) / 256, 256, 0, stream>>>(hidden, hb, T_ * HID / 4);
  conv_bf16<<<(QKVD * HID / 4) / 256, 256, 0, stream>>>(wqkv, wqkvb, QKVD * HID / 4);
  conv_bf16<<<(HID * HID / 4) / 256, 256, 0, stream>>>(wo, wob, HID * HID / 4);

  dim3 g1(QKVD / 256, T_ / 256);
  gemm_bt<true><<<g1, 512, 0, stream>>>(hb, wqkvb, qkv, T_, QKVD, HID);

  rope_scatter<<<T_, 256, 0, stream>>>(qkv, cosb, sinb, slots, qb, kb, vb, kc_out, vc_out);

  transpose_v<<<B_ * KVH_ * 16 * 2, 256, 0, stream>>>(vb, vt);

  attn_fused<<<B_ * H_ * (S_ / 64), 256, 0, stream>>>(qb, kb, vt, ob);

  dim3 g2(HID / 256, T_ / 256);
  gemm_bt<false><<<g2, 512, 0, stream>>>(ob, wob, out, T_, HID, HID);
}